// Round 1
// baseline (18039.177 us; speedup 1.0000x reference)
//
#include <hip/hip_runtime.h>
#include <hip/hip_bf16.h>
#include <hip/hip_cooperative_groups.h>

namespace cg = cooperative_groups;

typedef __attribute__((ext_vector_type(8))) short s8;
typedef __attribute__((ext_vector_type(4))) float f4;

#define DEVI static __device__ __forceinline__

DEVI float bf2f(short u) {
  union { float f; unsigned int i; } v;
  v.i = ((unsigned int)(unsigned short)u) << 16;
  return v.f;
}
DEVI short f2bf(float f) {
  union { float f; unsigned int i; } v; v.f = f;
  unsigned int r = v.i + 0x7fffu + ((v.i >> 16) & 1u);
  return (short)(r >> 16);
}
DEVI void gload_lds16(const void* g, void* l) {
  __builtin_amdgcn_global_load_lds(
      (const __attribute__((address_space(1))) unsigned int*)g,
      (__attribute__((address_space(3))) unsigned int*)l, 16, 0, 0);
}
DEVI float sigm(float x) { return 1.f / (1.f + __expf(-x)); }

// ---------------- converts ----------------
__global__ void k_f32_to_bf16(const float* __restrict__ in, short* __restrict__ out, long n) {
  long i = ((long)blockIdx.x * blockDim.x + threadIdx.x) * 8;
  if (i >= n) return;
  float4 a = *(const float4*)(in + i);
  float4 b = *(const float4*)(in + i + 4);
  s8 o;
  o[0] = f2bf(a.x); o[1] = f2bf(a.y); o[2] = f2bf(a.z); o[3] = f2bf(a.w);
  o[4] = f2bf(b.x); o[5] = f2bf(b.y); o[6] = f2bf(b.z); o[7] = f2bf(b.w);
  *(s8*)(out + i) = o;
}

// src [1024][1024] f32 row-major [k][n]  ->  dst [1024][1024] bf16 at [n][k]
__global__ void k_transpose_c(const float* __restrict__ src, short* __restrict__ dst) {
  __shared__ float tile[32][33];
  int n0 = blockIdx.x * 32, k0 = blockIdx.y * 32;
  int lx = threadIdx.x & 31, ly = threadIdx.x >> 5;  // ly 0..7
#pragma unroll
  for (int r = 0; r < 32; r += 8)
    tile[ly + r][lx] = src[(long)(k0 + ly + r) * 1024 + n0 + lx];
  __syncthreads();
#pragma unroll
  for (int r = 0; r < 32; r += 8)
    dst[(long)(n0 + ly + r) * 1024 + k0 + lx] = f2bf(tile[lx][ly + r]);
}

__global__ void k_bcat(const float* __restrict__ b0, const float* __restrict__ b1,
                       const float* __restrict__ b2, const float* __restrict__ b3,
                       float* __restrict__ o) {
  int i = blockIdx.x * 256 + threadIdx.x;  // 0..4095
  int j = i & 1023;
  float v;
  switch (i >> 10) { case 0: v = b0[j]; break; case 1: v = b1[j]; break;
                     case 2: v = b2[j]; break; default: v = b3[j]; }
  o[i] = v;
}

// ---------------- bf16 GEMM: C[M][N] = A[M][K] @ Bt[N][K]^T + bias ----------------
// 128x128 tile, BK=32, 4 waves (2x2 of 64x64), global_load_lds w=16, XOR swizzle.
template <typename OutT>
__global__ __launch_bounds__(256) void k_gemm_bt(
    const short* __restrict__ A, const short* __restrict__ Bt,
    const float* __restrict__ bias, OutT* __restrict__ C,
    int M, int N, int K) {
  __shared__ __align__(16) char As[8192];
  __shared__ __align__(16) char Bs[8192];
  const int tid = threadIdx.x;
  const int wid = tid >> 6, lane = tid & 63;
  const int lr = lane & 15, lk = lane >> 4;
  const int wy = wid >> 1, wx = wid & 1;
  const long bm = (long)blockIdx.y * 128, bn = (long)blockIdx.x * 128;
  const char* Ab = (const char*)A;
  const char* Bb = (const char*)Bt;
  f4 acc[4][4];
#pragma unroll
  for (int i = 0; i < 4; ++i)
#pragma unroll
    for (int j = 0; j < 4; ++j) acc[i][j] = f4{0.f, 0.f, 0.f, 0.f};

  for (int k0 = 0; k0 < K; k0 += 32) {
#pragma unroll
    for (int p = 0; p < 2; ++p) {
      int off = p * 4096 + tid * 16;
      int r = off >> 6, cb = off & 63;
      int sw = cb ^ ((r & 3) << 4);
      gload_lds16(Ab + ((bm + r) * K + k0) * 2 + sw, As + p * 4096 + wid * 1024);
      gload_lds16(Bb + ((bn + r) * K + k0) * 2 + sw, Bs + p * 4096 + wid * 1024);
    }
    __syncthreads();
    s8 af[4], bfr[4];
#pragma unroll
    for (int mi = 0; mi < 4; ++mi) {
      int r = wy * 64 + mi * 16 + lr;
      int x = r * 64 + lk * 16;
      af[mi] = *(const s8*)(As + (x ^ ((r & 3) << 4)));
    }
#pragma unroll
    for (int ni = 0; ni < 4; ++ni) {
      int r = wx * 64 + ni * 16 + lr;
      int x = r * 64 + lk * 16;
      bfr[ni] = *(const s8*)(Bs + (x ^ ((r & 3) << 4)));
    }
#pragma unroll
    for (int mi = 0; mi < 4; ++mi)
#pragma unroll
      for (int ni = 0; ni < 4; ++ni)
        acc[mi][ni] = __builtin_amdgcn_mfma_f32_16x16x32_bf16(af[mi], bfr[ni], acc[mi][ni], 0, 0, 0);
    __syncthreads();
  }
#pragma unroll
  for (int mi = 0; mi < 4; ++mi)
#pragma unroll
    for (int ni = 0; ni < 4; ++ni)
#pragma unroll
      for (int j = 0; j < 4; ++j) {
        long row = bm + wy * 64 + mi * 16 + lk * 4 + j;
        long col = bn + wx * 64 + ni * 16 + lr;
        float v = acc[mi][ni][j] + bias[col];
        if constexpr (sizeof(OutT) == 2) C[row * N + col] = f2bf(v);
        else                              C[row * N + col] = v;
      }
}

// ---------------- persistent LSTM recurrence ----------------
// 256 WGs x 256 threads. WG -> (rg = 16 batch rows, ug = 16 hidden units).
// wave g in 0..3 owns gate g (i,f,o,c). Recurrent weights live in registers.
// h carried as bf16 hi+lo (double buffered in global). c in one VGPR/thread.
__global__ __launch_bounds__(256, 1) void k_lstm_rec(
    const short* __restrict__ XG,   // [32768][4096]  (m = b*512+t)
    const short* __restrict__ Wht,  // [4096][1024]   ([gate*1024+u][k])
    short* __restrict__ hhi,        // [2][64][1024]
    short* __restrict__ hlo,        // [2][64][1024]
    short* __restrict__ HS) {       // [32768][1024]
  __shared__ __align__(16) char hA[65536];  // [hi|lo], each [16 rows][1024] bf16, XOR-swizzled
  __shared__ float pre[1024];               // [4 gates][16 rows][16 units]
  const int w = blockIdx.x;
  const int rg = (w & 7) >> 1;              // row-group clusters per XCD pair (speed-only)
  const int ug = (w >> 3) + ((w & 1) << 5);
  const int tid = threadIdx.x;
  const int g = tid >> 6;
  const int lane = tid & 63;
  const int lr = lane & 15, lk = lane >> 4;

  // persistent recurrent-weight B-fragments: 32 chunks x bf16x8
  s8 wf[32];
  {
    const short* wrow = Wht + ((long)(g * 1024 + ug * 16 + lr)) * 1024 + lk * 8;
#pragma unroll
    for (int kc = 0; kc < 32; ++kc) wf[kc] = *(const s8*)(wrow + kc * 32);
  }
  // zero both h ping-pong buffers
  {
    int idx = w * 256 + tid;
    hhi[idx] = 0; hhi[idx + 65536] = 0;
    hlo[idx] = 0; hlo[idx + 65536] = 0;
  }
  float c = 0.f;
  cg::grid_group grid = cg::this_grid();
  grid.sync();

  const int r_ew = tid >> 4, u_ew = tid & 15;
  for (int t = 0; t < 512; ++t) {
    const int p = t & 1;
    // stage h rows [rg*16, rg*16+16), hi+lo, into swizzled LDS
    {
      const char* srcHi = (const char*)(hhi + p * 65536 + rg * 16384);
      const char* srcLo = (const char*)(hlo + p * 65536 + rg * 16384);
#pragma unroll
      for (int pass = 0; pass < 8; ++pass) {
        int o = pass * 4096 + tid * 16;
        int s = o ^ (((o >> 11) & 7) << 4);
        gload_lds16(srcHi + s, hA + pass * 4096 + g * 1024);
        gload_lds16(srcLo + s, hA + 32768 + pass * 4096 + g * 1024);
      }
    }
    // accumulator init from XG (C/D layout: col=lane&15, row=(lane>>4)*4+j)
    f4 acc;
    {
      const short* xg = XG + ((long)((rg * 16 + lk * 4) * 512 + t)) * 4096 + g * 1024 + ug * 16 + lr;
#pragma unroll
      for (int j = 0; j < 4; ++j) acc[j] = bf2f(xg[(long)j * 512 * 4096]);
    }
    __syncthreads();  // drains vmcnt: staged h visible
#pragma unroll
    for (int kc = 0; kc < 32; ++kc) {
      int x = lr * 2048 + kc * 64 + lk * 16;
      int a = x ^ ((lr & 7) << 4);
      s8 ah = *(const s8*)(hA + a);
      s8 al = *(const s8*)(hA + 32768 + a);
      acc = __builtin_amdgcn_mfma_f32_16x16x32_bf16(ah, wf[kc], acc, 0, 0, 0);
      acc = __builtin_amdgcn_mfma_f32_16x16x32_bf16(al, wf[kc], acc, 0, 0, 0);
    }
    // exchange the 4 gate pre-activations through LDS
    {
      float* pg = pre + g * 256;
#pragma unroll
      for (int j = 0; j < 4; ++j) pg[(lk * 4 + j) * 16 + lr] = acc[j];
    }
    __syncthreads();
    // elementwise state update: thread owns (r_ew, u_ew)
    {
      float pi = pre[0   + r_ew * 16 + u_ew];
      float pf = pre[256 + r_ew * 16 + u_ew];
      float po = pre[512 + r_ew * 16 + u_ew];
      float pc = pre[768 + r_ew * 16 + u_ew];
      float fi = sigm(pi), ff = sigm(pf), fo = sigm(po);
      float ch = tanhf(pc);
      c = ff * c + fi * ch;
      float h = fo * tanhf(c);
      short hh = f2bf(h);
      short hl = f2bf(h - bf2f(hh));
      int hidx = (p ^ 1) * 65536 + (rg * 16 + r_ew) * 1024 + ug * 16 + u_ew;
      hhi[hidx] = hh;
      hlo[hidx] = hl;
      HS[((long)(rg * 16 + r_ew) * 512 + t) * 1024 + ug * 16 + u_ew] = hh;
    }
    grid.sync();
  }
}

// ---------------- launch ----------------
extern "C" void kernel_launch(void* const* d_in, const int* in_sizes, int n_in,
                              void* d_out, int out_size, void* d_ws, size_t ws_size,
                              hipStream_t stream) {
  const float* x = (const float*)d_in[0];
  const float* Wx[4] = {(const float*)d_in[1], (const float*)d_in[4], (const float*)d_in[7], (const float*)d_in[10]};
  const float* Wh[4] = {(const float*)d_in[2], (const float*)d_in[5], (const float*)d_in[8], (const float*)d_in[11]};
  const float* bg[4] = {(const float*)d_in[3], (const float*)d_in[6], (const float*)d_in[9], (const float*)d_in[12]};
  const float* Why = (const float*)d_in[13];
  const float* by  = (const float*)d_in[14];

  char* ws = (char*)d_ws;                     // layout (bytes):
  short* xbf  = (short*)(ws);                 // 67,108,864  x as bf16 [32768][1024]
  short* Wxt  = (short*)(ws + 67108864);      //  8,388,608  [4096][1024]
  short* Wht  = (short*)(ws + 75497472);      //  8,388,608  [4096][1024]
  short* Whyt = (short*)(ws + 83886080);      //  2,097,152  [1024][1024]
  float* bcat = (float*)(ws + 85983232);      //     16,384
  short* XG   = (short*)(ws + 85999616);      // 268,435,456 [32768][4096]
  short* HS   = (short*)(ws + 354435072);     // 67,108,864  [32768][1024]
  short* hhi  = (short*)(ws + 421543936);     //    262,144
  short* hlo  = (short*)(ws + 421806080);     //    262,144  total ~422 MB

  hipLaunchKernelGGL(k_f32_to_bf16, dim3(16384), dim3(256), 0, stream, x, xbf, (long)33554432);
  for (int gi = 0; gi < 4; ++gi) {
    hipLaunchKernelGGL(k_transpose_c, dim3(32, 32), dim3(256), 0, stream, Wx[gi], Wxt + (long)gi * 1048576);
    hipLaunchKernelGGL(k_transpose_c, dim3(32, 32), dim3(256), 0, stream, Wh[gi], Wht + (long)gi * 1048576);
  }
  hipLaunchKernelGGL(k_transpose_c, dim3(32, 32), dim3(256), 0, stream, Why, Whyt);
  hipLaunchKernelGGL(k_bcat, dim3(16), dim3(256), 0, stream, bg[0], bg[1], bg[2], bg[3], bcat);

  hipLaunchKernelGGL((k_gemm_bt<short>), dim3(32, 256), dim3(256), 0, stream,
                     xbf, Wxt, bcat, XG, 32768, 4096, 1024);

  {
    void* args[] = { (void*)&XG, (void*)&Wht, (void*)&hhi, (void*)&hlo, (void*)&HS };
    hipLaunchCooperativeKernel((void*)k_lstm_rec, dim3(256), dim3(256), args, 0, stream);
  }

  hipLaunchKernelGGL((k_gemm_bt<float>), dim3(8, 256), dim3(256), 0, stream,
                     HS, Whyt, by, (float*)d_out, 32768, 1024, 1024);
}

// Round 2
// 8400.729 us; speedup vs baseline: 2.1473x; 2.1473x over previous
//
#include <hip/hip_runtime.h>
#include <hip/hip_bf16.h>

typedef __attribute__((ext_vector_type(8))) short s8;
typedef __attribute__((ext_vector_type(4))) float f4;

#define DEVI static __device__ __forceinline__

DEVI float bf2f(short u) {
  union { float f; unsigned int i; } v;
  v.i = ((unsigned int)(unsigned short)u) << 16;
  return v.f;
}
DEVI short f2bf(float f) {
  union { float f; unsigned int i; } v; v.f = f;
  unsigned int r = v.i + 0x7fffu + ((v.i >> 16) & 1u);
  return (short)(r >> 16);
}
DEVI void gload_lds16(const void* g, void* l) {
  __builtin_amdgcn_global_load_lds(
      (const __attribute__((address_space(1))) unsigned int*)g,
      (__attribute__((address_space(3))) unsigned int*)l, 16, 0, 0);
}
DEVI float sigm(float x) { return 1.f / (1.f + __expf(-x)); }

// ---------------- converts ----------------
// x [64][512][1024] f32  ->  xbf [512][64][1024] bf16 (t-major rows)
__global__ void k_x_relayout(const float* __restrict__ in, short* __restrict__ out) {
  long idx8 = (long)blockIdx.x * blockDim.x + threadIdx.x;
  long E = idx8 * 8;                 // element index in OUT space
  long row = E >> 10;                // row_out = t*64 + b
  long col = E & 1023;
  long t = row >> 6, b = row & 63;
  const float* src = in + ((b << 9) + t) * 1024 + col;
  float4 a = *(const float4*)(src);
  float4 c = *(const float4*)(src + 4);
  s8 o;
  o[0] = f2bf(a.x); o[1] = f2bf(a.y); o[2] = f2bf(a.z); o[3] = f2bf(a.w);
  o[4] = f2bf(c.x); o[5] = f2bf(c.y); o[6] = f2bf(c.z); o[7] = f2bf(c.w);
  *(s8*)(out + E) = o;
}

// src [1024][1024] f32 row-major [k][n]  ->  dst [1024][1024] bf16 at [n][k]
__global__ void k_transpose_c(const float* __restrict__ src, short* __restrict__ dst) {
  __shared__ float tile[32][33];
  int n0 = blockIdx.x * 32, k0 = blockIdx.y * 32;
  int lx = threadIdx.x & 31, ly = threadIdx.x >> 5;  // ly 0..7
#pragma unroll
  for (int r = 0; r < 32; r += 8)
    tile[ly + r][lx] = src[(long)(k0 + ly + r) * 1024 + n0 + lx];
  __syncthreads();
#pragma unroll
  for (int r = 0; r < 32; r += 8)
    dst[(long)(n0 + ly + r) * 1024 + k0 + lx] = f2bf(tile[lx][ly + r]);
}

__global__ void k_bcat(const float* __restrict__ b0, const float* __restrict__ b1,
                       const float* __restrict__ b2, const float* __restrict__ b3,
                       float* __restrict__ o) {
  int i = blockIdx.x * 256 + threadIdx.x;  // 0..4095
  int j = i & 1023;
  float v;
  switch (i >> 10) { case 0: v = b0[j]; break; case 1: v = b1[j]; break;
                     case 2: v = b2[j]; break; default: v = b3[j]; }
  o[i] = v;
}

// ---------------- bf16 GEMM: C[M][N] = A[M][K] @ Bt[N][K]^T + bias ----------------
// 128x128 tile, BK=32, 4 waves (2x2 of 64x64), global_load_lds w=16, XOR swizzle.
// REMAP: output row (t*64+b) -> (b*512+t)
template <typename OutT, bool REMAP>
__global__ __launch_bounds__(256) void k_gemm_bt(
    const short* __restrict__ A, const short* __restrict__ Bt,
    const float* __restrict__ bias, OutT* __restrict__ C,
    int M, int N, int K) {
  __shared__ __align__(16) char As[8192];
  __shared__ __align__(16) char Bs[8192];
  const int tid = threadIdx.x;
  const int wid = tid >> 6, lane = tid & 63;
  const int lr = lane & 15, lk = lane >> 4;
  const int wy = wid >> 1, wx = wid & 1;
  const long bm = (long)blockIdx.y * 128, bn = (long)blockIdx.x * 128;
  const char* Ab = (const char*)A;
  const char* Bb = (const char*)Bt;
  f4 acc[4][4];
#pragma unroll
  for (int i = 0; i < 4; ++i)
#pragma unroll
    for (int j = 0; j < 4; ++j) acc[i][j] = f4{0.f, 0.f, 0.f, 0.f};

  for (int k0 = 0; k0 < K; k0 += 32) {
#pragma unroll
    for (int p = 0; p < 2; ++p) {
      int off = p * 4096 + tid * 16;
      int r = off >> 6, cb = off & 63;
      int sw = cb ^ ((r & 3) << 4);
      gload_lds16(Ab + ((bm + r) * K + k0) * 2 + sw, As + p * 4096 + wid * 1024);
      gload_lds16(Bb + ((bn + r) * K + k0) * 2 + sw, Bs + p * 4096 + wid * 1024);
    }
    __syncthreads();
    s8 af[4], bfr[4];
#pragma unroll
    for (int mi = 0; mi < 4; ++mi) {
      int r = wy * 64 + mi * 16 + lr;
      int x = r * 64 + lk * 16;
      af[mi] = *(const s8*)(As + (x ^ ((r & 3) << 4)));
    }
#pragma unroll
    for (int ni = 0; ni < 4; ++ni) {
      int r = wx * 64 + ni * 16 + lr;
      int x = r * 64 + lk * 16;
      bfr[ni] = *(const s8*)(Bs + (x ^ ((r & 3) << 4)));
    }
#pragma unroll
    for (int mi = 0; mi < 4; ++mi)
#pragma unroll
      for (int ni = 0; ni < 4; ++ni)
        acc[mi][ni] = __builtin_amdgcn_mfma_f32_16x16x32_bf16(af[mi], bfr[ni], acc[mi][ni], 0, 0, 0);
    __syncthreads();
  }
#pragma unroll
  for (int mi = 0; mi < 4; ++mi)
#pragma unroll
    for (int ni = 0; ni < 4; ++ni)
#pragma unroll
      for (int j = 0; j < 4; ++j) {
        long row = bm + wy * 64 + mi * 16 + lk * 4 + j;
        long col = bn + wx * 64 + ni * 16 + lr;
        float v = acc[mi][ni][j] + bias[col];
        long orow = REMAP ? ((row & 63) * 512 + (row >> 6)) : row;
        if constexpr (sizeof(OutT) == 2) C[orow * N + col] = f2bf(v);
        else                              C[orow * N + col] = v;
      }
}

// ---------------- one LSTM timestep ----------------
// grid 64 x 512 threads. WG = (rb: 32 batch rows) x (ub: 32 units) x 4 gates.
// 8 waves: wave (g = wid&3, uh = wid>>2) -> gate g, units ub*32+uh*16+[0,16).
// Weights -> registers (L2-resident across steps); h hi/lo -> swizzled LDS.
__global__ __launch_bounds__(512, 1) void k_step(
    const short* __restrict__ XGt,   // [64][4096] slice at time t (bias included)
    const short* __restrict__ Wht,   // [4096][1024]
    const short* __restrict__ hci,   // h_t hi  [64][1024]
    const short* __restrict__ hcl,   // h_t lo
    short* __restrict__ hni,         // h_{t+1} hi
    short* __restrict__ hnl,         // h_{t+1} lo
    float* __restrict__ cst,         // c state [64][1024] fp32 (in-place)
    short* __restrict__ HSt) {       // [64][1024] slice at time t
  __shared__ __align__(16) char hA[131072];   // hi [32][2048B] swz; lo at +65536
  __shared__ float pre[4096];                  // [4 gates][32 rows][32 units]
  const int tid = threadIdx.x;
  const int wid = tid >> 6, lane = tid & 63;
  const int lr = lane & 15, lk = lane >> 4;
  const int g = wid & 3, uh = wid >> 2;
  const int rb = blockIdx.x & 1, ub = blockIdx.x >> 1;

  // stage h rows [rb*32, +32), hi+lo, into XOR-swizzled LDS (issue early)
  {
    const char* sHi = (const char*)hci + rb * 65536;
    const char* sLo = (const char*)hcl + rb * 65536;
#pragma unroll
    for (int pass = 0; pass < 8; ++pass) {
      int o = pass * 8192 + tid * 16;          // linear LDS dest offset
      int s = o ^ (((o >> 11) & 7) << 4);      // pre-swizzled global source
      gload_lds16(sHi + s, hA + pass * 8192 + wid * 1024);
      gload_lds16(sLo + s, hA + 65536 + pass * 8192 + wid * 1024);
    }
  }

  // recurrent-weight B-fragments: 32 chunks x bf16x8 (128 VGPR)
  s8 wf[32];
  {
    const short* wrow = Wht + ((long)(g * 1024 + ub * 32 + uh * 16 + lr)) * 1024 + lk * 8;
#pragma unroll
    for (int kc = 0; kc < 32; ++kc) wf[kc] = *(const s8*)(wrow + kc * 32);
  }

  // accumulator init from XG (C/D layout: col=lane&15, row=(lane>>4)*4+j)
  f4 acc[2];
  {
    const int ucol = g * 1024 + ub * 32 + uh * 16 + lr;
#pragma unroll
    for (int mi = 0; mi < 2; ++mi)
#pragma unroll
      for (int j = 0; j < 4; ++j)
        acc[mi][j] = bf2f(XGt[(long)(rb * 32 + mi * 16 + lk * 4 + j) * 4096 + ucol]);
  }
  __syncthreads();  // drains vmcnt: staged h visible

#pragma unroll
  for (int kc = 0; kc < 32; ++kc) {
#pragma unroll
    for (int mi = 0; mi < 2; ++mi) {
      int r = mi * 16 + lr;
      int x = r * 2048 + kc * 64 + lk * 16;
      int a = x ^ ((r & 7) << 4);
      s8 ah = *(const s8*)(hA + a);
      s8 al = *(const s8*)(hA + 65536 + a);
      acc[mi] = __builtin_amdgcn_mfma_f32_16x16x32_bf16(ah, wf[kc], acc[mi], 0, 0, 0);
      acc[mi] = __builtin_amdgcn_mfma_f32_16x16x32_bf16(al, wf[kc], acc[mi], 0, 0, 0);
    }
  }

  // exchange the 4 gate pre-activations through LDS
#pragma unroll
  for (int mi = 0; mi < 2; ++mi)
#pragma unroll
    for (int j = 0; j < 4; ++j)
      pre[g * 1024 + (mi * 16 + lk * 4 + j) * 32 + uh * 16 + lr] = acc[mi][j];
  __syncthreads();

  // elementwise state update: thread -> (row = tid>>4, units (tid&15)*2 + {0,1})
  {
    int row = tid >> 4;
    int u0 = (tid & 15) * 2;
#pragma unroll
    for (int e = 0; e < 2; ++e) {
      int u = u0 + e;
      float pi = pre[0 * 1024 + row * 32 + u];
      float pf = pre[1 * 1024 + row * 32 + u];
      float po = pre[2 * 1024 + row * 32 + u];
      float pc = pre[3 * 1024 + row * 32 + u];
      long idx = (long)(rb * 32 + row) * 1024 + ub * 32 + u;
      float c = cst[idx];
      float fi = sigm(pi), ff = sigm(pf), fo = sigm(po);
      float ch = tanhf(pc);
      c = ff * c + fi * ch;
      cst[idx] = c;
      float h = fo * tanhf(c);
      short hh = f2bf(h);
      short hl = f2bf(h - bf2f(hh));
      hni[idx] = hh;
      hnl[idx] = hl;
      HSt[idx] = hh;
    }
  }
}

// ---------------- launch ----------------
extern "C" void kernel_launch(void* const* d_in, const int* in_sizes, int n_in,
                              void* d_out, int out_size, void* d_ws, size_t ws_size,
                              hipStream_t stream) {
  const float* x = (const float*)d_in[0];
  const float* Wx[4] = {(const float*)d_in[1], (const float*)d_in[4], (const float*)d_in[7], (const float*)d_in[10]};
  const float* Wh[4] = {(const float*)d_in[2], (const float*)d_in[5], (const float*)d_in[8], (const float*)d_in[11]};
  const float* bg[4] = {(const float*)d_in[3], (const float*)d_in[6], (const float*)d_in[9], (const float*)d_in[12]};
  const float* Why = (const float*)d_in[13];
  const float* by  = (const float*)d_in[14];

  char* ws = (char*)d_ws;                     // layout (bytes):
  short* xbf  = (short*)(ws);                 // 67,108,864  x bf16 [512][64][1024] (t-major)
  short* HS   = (short*)(ws);                 // reuses xbf region (xbf dead after big GEMM)
  short* Wxt  = (short*)(ws + 67108864);      //  8,388,608  [4096][1024]
  short* Wht  = (short*)(ws + 75497472);      //  8,388,608  [4096][1024]
  short* Whyt = (short*)(ws + 83886080);      //  2,097,152  [1024][1024]
  float* bcat = (float*)(ws + 85983232);      //     16,384
  short* XG   = (short*)(ws + 85999616);      // 268,435,456 [512][64][4096]
  short* hhi  = (short*)(ws + 354435072);     //    262,144  [2][64][1024]
  short* hlo  = (short*)(ws + 354697216);     //    262,144
  float* cst  = (float*)(ws + 354959360);     //    262,144  total ~355 MB

  hipLaunchKernelGGL(k_x_relayout, dim3(16384), dim3(256), 0, stream, x, xbf);
  for (int gi = 0; gi < 4; ++gi) {
    hipLaunchKernelGGL(k_transpose_c, dim3(32, 32), dim3(256), 0, stream, Wx[gi], Wxt + (long)gi * 1048576);
    hipLaunchKernelGGL(k_transpose_c, dim3(32, 32), dim3(256), 0, stream, Wh[gi], Wht + (long)gi * 1048576);
  }
  hipLaunchKernelGGL(k_transpose_c, dim3(32, 32), dim3(256), 0, stream, Why, Whyt);
  hipLaunchKernelGGL(k_bcat, dim3(16), dim3(256), 0, stream, bg[0], bg[1], bg[2], bg[3], bcat);

  hipLaunchKernelGGL((k_gemm_bt<short, false>), dim3(32, 256), dim3(256), 0, stream,
                     xbf, Wxt, bcat, XG, 32768, 4096, 1024);

  // zero h_0 (both buffers for safety) and c_0
  hipMemsetAsync(hhi, 0, 262144, stream);
  hipMemsetAsync(hlo, 0, 262144, stream);
  hipMemsetAsync(cst, 0, 262144, stream);

  for (int t = 0; t < 512; ++t) {
    const short* XGt = XG + (long)t * 64 * 4096;
    short* HSt = HS + (long)t * 64 * 1024;
    int cur = t & 1, nxt = cur ^ 1;
    hipLaunchKernelGGL(k_step, dim3(64), dim3(512), 0, stream,
                       XGt, Wht,
                       (const short*)(hhi + cur * 65536), (const short*)(hlo + cur * 65536),
                       hhi + nxt * 65536, hlo + nxt * 65536,
                       cst, HSt);
  }

  hipLaunchKernelGGL((k_gemm_bt<float, true>), dim3(8, 256), dim3(256), 0, stream,
                     HS, Whyt, by, (float*)d_out, 32768, 1024, 1024);
}

// Round 3
// 5331.184 us; speedup vs baseline: 3.3837x; 1.5758x over previous
//
#include <hip/hip_runtime.h>
#include <hip/hip_bf16.h>

typedef __attribute__((ext_vector_type(8))) short s8;
typedef __attribute__((ext_vector_type(4))) float f4;

#define DEVI static __device__ __forceinline__

DEVI float bf2f(short u) {
  union { float f; unsigned int i; } v;
  v.i = ((unsigned int)(unsigned short)u) << 16;
  return v.f;
}
DEVI short f2bf(float f) {
  union { float f; unsigned int i; } v; v.f = f;
  unsigned int r = v.i + 0x7fffu + ((v.i >> 16) & 1u);
  return (short)(r >> 16);
}
DEVI void gload_lds16(const void* g, void* l) {
  __builtin_amdgcn_global_load_lds(
      (const __attribute__((address_space(1))) unsigned int*)g,
      (__attribute__((address_space(3))) unsigned int*)l, 16, 0, 0);
}
DEVI float sigm(float x) { return 1.f / (1.f + __expf(-x)); }

// ---------------- converts ----------------
// x [64][512][1024] f32  ->  xbf [512][64][1024] bf16 (t-major rows)
__global__ void k_x_relayout(const float* __restrict__ in, short* __restrict__ out) {
  long idx8 = (long)blockIdx.x * blockDim.x + threadIdx.x;
  long E = idx8 * 8;                 // element index in OUT space
  long row = E >> 10;                // row_out = t*64 + b
  long col = E & 1023;
  long t = row >> 6, b = row & 63;
  const float* src = in + ((b << 9) + t) * 1024 + col;
  float4 a = *(const float4*)(src);
  float4 c = *(const float4*)(src + 4);
  s8 o;
  o[0] = f2bf(a.x); o[1] = f2bf(a.y); o[2] = f2bf(a.z); o[3] = f2bf(a.w);
  o[4] = f2bf(c.x); o[5] = f2bf(c.y); o[6] = f2bf(c.z); o[7] = f2bf(c.w);
  *(s8*)(out + E) = o;
}

// src [1024][1024] f32 row-major [k][n]  ->  dst [1024][1024] bf16 at [n][k]
__global__ void k_transpose_c(const float* __restrict__ src, short* __restrict__ dst) {
  __shared__ float tile[32][33];
  int n0 = blockIdx.x * 32, k0 = blockIdx.y * 32;
  int lx = threadIdx.x & 31, ly = threadIdx.x >> 5;  // ly 0..7
#pragma unroll
  for (int r = 0; r < 32; r += 8)
    tile[ly + r][lx] = src[(long)(k0 + ly + r) * 1024 + n0 + lx];
  __syncthreads();
#pragma unroll
  for (int r = 0; r < 32; r += 8)
    dst[(long)(n0 + ly + r) * 1024 + k0 + lx] = f2bf(tile[lx][ly + r]);
}

__global__ void k_bcat(const float* __restrict__ b0, const float* __restrict__ b1,
                       const float* __restrict__ b2, const float* __restrict__ b3,
                       float* __restrict__ o) {
  int i = blockIdx.x * 256 + threadIdx.x;  // 0..4095
  int j = i & 1023;
  float v;
  switch (i >> 10) { case 0: v = b0[j]; break; case 1: v = b1[j]; break;
                     case 2: v = b2[j]; break; default: v = b3[j]; }
  o[i] = v;
}

// ---------------- bf16 GEMM: C[M][N] = A[M][K] @ Bt[N][K]^T + bias ----------------
template <typename OutT, bool REMAP>
__global__ __launch_bounds__(256) void k_gemm_bt(
    const short* __restrict__ A, const short* __restrict__ Bt,
    const float* __restrict__ bias, OutT* __restrict__ C,
    int M, int N, int K) {
  __shared__ __align__(16) char As[8192];
  __shared__ __align__(16) char Bs[8192];
  const int tid = threadIdx.x;
  const int wid = tid >> 6, lane = tid & 63;
  const int lr = lane & 15, lk = lane >> 4;
  const int wy = wid >> 1, wx = wid & 1;
  const long bm = (long)blockIdx.y * 128, bn = (long)blockIdx.x * 128;
  const char* Ab = (const char*)A;
  const char* Bb = (const char*)Bt;
  f4 acc[4][4];
#pragma unroll
  for (int i = 0; i < 4; ++i)
#pragma unroll
    for (int j = 0; j < 4; ++j) acc[i][j] = f4{0.f, 0.f, 0.f, 0.f};

  for (int k0 = 0; k0 < K; k0 += 32) {
#pragma unroll
    for (int p = 0; p < 2; ++p) {
      int off = p * 4096 + tid * 16;
      int r = off >> 6, cb = off & 63;
      int sw = cb ^ ((r & 3) << 4);
      gload_lds16(Ab + ((bm + r) * K + k0) * 2 + sw, As + p * 4096 + wid * 1024);
      gload_lds16(Bb + ((bn + r) * K + k0) * 2 + sw, Bs + p * 4096 + wid * 1024);
    }
    __syncthreads();
    s8 af[4], bfr[4];
#pragma unroll
    for (int mi = 0; mi < 4; ++mi) {
      int r = wy * 64 + mi * 16 + lr;
      int x = r * 64 + lk * 16;
      af[mi] = *(const s8*)(As + (x ^ ((r & 3) << 4)));
    }
#pragma unroll
    for (int ni = 0; ni < 4; ++ni) {
      int r = wx * 64 + ni * 16 + lr;
      int x = r * 64 + lk * 16;
      bfr[ni] = *(const s8*)(Bs + (x ^ ((r & 3) << 4)));
    }
#pragma unroll
    for (int mi = 0; mi < 4; ++mi)
#pragma unroll
      for (int ni = 0; ni < 4; ++ni)
        acc[mi][ni] = __builtin_amdgcn_mfma_f32_16x16x32_bf16(af[mi], bfr[ni], acc[mi][ni], 0, 0, 0);
    __syncthreads();
  }
#pragma unroll
  for (int mi = 0; mi < 4; ++mi)
#pragma unroll
    for (int ni = 0; ni < 4; ++ni)
#pragma unroll
      for (int j = 0; j < 4; ++j) {
        long row = bm + wy * 64 + mi * 16 + lk * 4 + j;
        long col = bn + wx * 64 + ni * 16 + lr;
        float v = acc[mi][ni][j] + bias[col];
        long orow = REMAP ? ((row & 63) * 512 + (row >> 6)) : row;
        if constexpr (sizeof(OutT) == 2) C[orow * N + col] = f2bf(v);
        else                              C[orow * N + col] = v;
      }
}

// ---------------- device-scope barrier (no shared counter) ----------------
// done[0..127]: per-WG arrival words. epoch at bar[512] (separate line).
DEVI void gbar(unsigned int* done, unsigned int* epoch, int wg, int tid, unsigned int target) {
  asm volatile("s_waitcnt vmcnt(0)" ::: "memory");  // drain sc1 stores to IF$
  __syncthreads();
  if (wg == 0) {
    if (tid == 0)
      __hip_atomic_store(&done[0], target, __ATOMIC_RELAXED, __HIP_MEMORY_SCOPE_AGENT);
    if (tid < 128) {
      int guard = 0;
      while (__hip_atomic_load(&done[tid], __ATOMIC_RELAXED, __HIP_MEMORY_SCOPE_AGENT) < target) {
        __builtin_amdgcn_s_sleep(4);
        if (++guard > (1 << 22)) break;
      }
    }
    __syncthreads();
    if (tid == 0)
      __hip_atomic_store(epoch, target, __ATOMIC_RELAXED, __HIP_MEMORY_SCOPE_AGENT);
  } else {
    if (tid == 0) {
      __hip_atomic_store(&done[wg], target, __ATOMIC_RELAXED, __HIP_MEMORY_SCOPE_AGENT);
      int guard = 0;
      while (__hip_atomic_load(epoch, __ATOMIC_RELAXED, __HIP_MEMORY_SCOPE_AGENT) < target) {
        __builtin_amdgcn_s_sleep(4);
        if (++guard > (1 << 22)) break;
      }
    }
    __syncthreads();
  }
}

// ---------------- persistent LSTM recurrence ----------------
// 128 WGs x 512 threads. WG = (rb = wg&3: 16 batch rows) x (ug = wg>>2: 32 units).
// Wave (g = wid&3, uh = wid>>2): gate g, unit cols ug*32+uh*16+[0,16).
// Weights in VGPRs for all 512 steps; c in a register; h (hi,lo packed u32)
// exchanged via relaxed agent-scope atomics (IF$-coherent).
__global__ __launch_bounds__(512, 2) void k_lstm_p(
    const short* __restrict__ XG,     // [512][64][4096] (bias folded in)
    const short* __restrict__ Wht,    // [4096][1024]
    unsigned int* __restrict__ hbuf,  // [2][64][1024] packed (hi<<16 | lo)
    unsigned int* __restrict__ bar,   // done[0..127], epoch at [512]
    short* __restrict__ HS) {         // [512][64][1024] bf16 (hi only)
  __shared__ __align__(16) char hHi[32768];  // [16][1024] bf16, XOR-swizzled
  __shared__ __align__(16) char hLo[32768];
  __shared__ float pre[4 * 16 * 33];          // [gate][row][unit], padded

  const int tid = threadIdx.x;
  const int wg = blockIdx.x;
  const int wid = tid >> 6, lane = tid & 63;
  const int lr = lane & 15, lk = lane >> 4;
  const int g = wid & 3, uh = wid >> 2;
  const int rb = wg & 3, ug = wg >> 2;
  const int gcol = g * 1024 + ug * 32 + uh * 16 + lr;  // gate-unit column

  // recurrent-weight B-fragments: 32 x bf16x8 = 128 VGPR, held all 512 steps
  s8 wf[32];
  {
    const short* wrow = Wht + (long)gcol * 1024 + lk * 8;
#pragma unroll
    for (int kc = 0; kc < 32; ++kc) wf[kc] = *(const s8*)(wrow + kc * 32);
  }

  // elementwise ownership: one (row, unit) per thread
  const int erow = tid >> 5, eu = tid & 31;
  const int growE = rb * 16 + erow;
  const int ucolE = ug * 32 + eu;
  float c = 0.f;

  // stage ownership
  const int srow = tid >> 5, sL = tid & 31;

  unsigned int* done = bar;
  unsigned int* epoch = bar + 512;

  // h0 = 0 (each WG covers its write region; union over WGs = full buffer)
  __hip_atomic_store(&hbuf[(long)growE * 1024 + ucolE], 0u,
                     __ATOMIC_RELAXED, __HIP_MEMORY_SCOPE_AGENT);
  gbar(done, epoch, wg, tid, 1u);

  for (int t = 0; t < 512; ++t) {
    const unsigned int* cur = hbuf + (t & 1) * 65536;
    unsigned int* nxt = hbuf + ((t + 1) & 1) * 65536;

    // XG prefetch for this step (consumed after MFMA chains)
    const short* xgp = XG + (long)t * 262144 + (long)(rb * 16 + lk * 4) * 4096 + gcol;
    short x0 = xgp[0], x1 = xgp[4096], x2 = xgp[8192], x3 = xgp[12288];

    // stage h rows [rb*16, +16): packed u64 loads -> split hi/lo -> swizzled LDS
    {
      const unsigned long long* src =
          (const unsigned long long*)(cur + (long)(rb * 16 + srow) * 1024);
#pragma unroll
      for (int i = 0; i < 16; ++i) {
        unsigned long long v = __hip_atomic_load(&src[sL + i * 32],
                                                 __ATOMIC_RELAXED, __HIP_MEMORY_SCOPE_AGENT);
        unsigned int w0 = (unsigned int)v, w1 = (unsigned int)(v >> 32);
        unsigned int hiW = __builtin_amdgcn_perm(w1, w0, 0x07060302u);
        unsigned int loW = __builtin_amdgcn_perm(w1, w0, 0x05040100u);
        int a = (srow * 2048 + sL * 4 + i * 128) ^ ((srow & 7) << 4);
        *(unsigned int*)(hHi + a) = hiW;
        *(unsigned int*)(hLo + a) = loW;
      }
    }
    __syncthreads();

    // 4 independent MFMA chains (16 deep each)
    f4 aHe{0.f, 0.f, 0.f, 0.f}, aHo{0.f, 0.f, 0.f, 0.f};
    f4 aLe{0.f, 0.f, 0.f, 0.f}, aLo{0.f, 0.f, 0.f, 0.f};
#pragma unroll
    for (int kc = 0; kc < 32; kc += 2) {
      int a0 = (lr * 2048 + kc * 64 + lk * 16) ^ ((lr & 7) << 4);
      int a1 = (lr * 2048 + (kc + 1) * 64 + lk * 16) ^ ((lr & 7) << 4);
      aHe = __builtin_amdgcn_mfma_f32_16x16x32_bf16(*(const s8*)(hHi + a0), wf[kc], aHe, 0, 0, 0);
      aHo = __builtin_amdgcn_mfma_f32_16x16x32_bf16(*(const s8*)(hHi + a1), wf[kc + 1], aHo, 0, 0, 0);
      aLe = __builtin_amdgcn_mfma_f32_16x16x32_bf16(*(const s8*)(hLo + a0), wf[kc], aLe, 0, 0, 0);
      aLo = __builtin_amdgcn_mfma_f32_16x16x32_bf16(*(const s8*)(hLo + a1), wf[kc + 1], aLo, 0, 0, 0);
    }
    float xg[4] = {bf2f(x0), bf2f(x1), bf2f(x2), bf2f(x3)};

    // exchange gate pre-activations (C/D layout: col=lr, row=lk*4+j)
#pragma unroll
    for (int j = 0; j < 4; ++j)
      pre[(g * 16 + lk * 4 + j) * 33 + uh * 16 + lr] =
          aHe[j] + aHo[j] + aLe[j] + aLo[j] + xg[j];
    __syncthreads();

    // elementwise state update
    {
      float pi = pre[(0 * 16 + erow) * 33 + eu];
      float pf = pre[(1 * 16 + erow) * 33 + eu];
      float po = pre[(2 * 16 + erow) * 33 + eu];
      float pc = pre[(3 * 16 + erow) * 33 + eu];
      float fi = sigm(pi), ff = sigm(pf), fo = sigm(po);
      float ch = tanhf(pc);
      c = ff * c + fi * ch;
      float h = fo * tanhf(c);
      short hh = f2bf(h);
      short hl = f2bf(h - bf2f(hh));
      unsigned int w = ((unsigned int)(unsigned short)hh << 16) | (unsigned short)(unsigned short)hl;
      __hip_atomic_store(&nxt[(long)growE * 1024 + ucolE], w,
                         __ATOMIC_RELAXED, __HIP_MEMORY_SCOPE_AGENT);
      HS[(long)t * 65536 + (long)growE * 1024 + ucolE] = hh;
    }
    gbar(done, epoch, wg, tid, (unsigned int)(t + 2));
  }
}

// ---------------- launch ----------------
extern "C" void kernel_launch(void* const* d_in, const int* in_sizes, int n_in,
                              void* d_out, int out_size, void* d_ws, size_t ws_size,
                              hipStream_t stream) {
  const float* x = (const float*)d_in[0];
  const float* Wx[4] = {(const float*)d_in[1], (const float*)d_in[4], (const float*)d_in[7], (const float*)d_in[10]};
  const float* Wh[4] = {(const float*)d_in[2], (const float*)d_in[5], (const float*)d_in[8], (const float*)d_in[11]};
  const float* bg[4] = {(const float*)d_in[3], (const float*)d_in[6], (const float*)d_in[9], (const float*)d_in[12]};
  const float* Why = (const float*)d_in[13];
  const float* by  = (const float*)d_in[14];

  char* ws = (char*)d_ws;                     // layout (bytes):
  short* xbf  = (short*)(ws);                 // 67,108,864  x bf16 [512][64][1024]
  short* HS   = (short*)(ws);                 // reuses xbf (dead after big GEMM)
  short* Wxt  = (short*)(ws + 67108864);      //  8,388,608
  short* Wht  = (short*)(ws + 75497472);      //  8,388,608
  short* Whyt = (short*)(ws + 83886080);      //  2,097,152
  float* bcat = (float*)(ws + 85983232);      //     16,384
  short* XG   = (short*)(ws + 85999616);      // 268,435,456 [512][64][4096]
  unsigned int* hbuf = (unsigned int*)(ws + 354435072);  // 524,288 [2][64][1024] u32
  unsigned int* bar  = (unsigned int*)(ws + 354959360);  //   4,096

  hipLaunchKernelGGL(k_x_relayout, dim3(16384), dim3(256), 0, stream, x, xbf);
  for (int gi = 0; gi < 4; ++gi) {
    hipLaunchKernelGGL(k_transpose_c, dim3(32, 32), dim3(256), 0, stream, Wx[gi], Wxt + (long)gi * 1048576);
    hipLaunchKernelGGL(k_transpose_c, dim3(32, 32), dim3(256), 0, stream, Wh[gi], Wht + (long)gi * 1048576);
  }
  hipLaunchKernelGGL(k_transpose_c, dim3(32, 32), dim3(256), 0, stream, Why, Whyt);
  hipLaunchKernelGGL(k_bcat, dim3(16), dim3(256), 0, stream, bg[0], bg[1], bg[2], bg[3], bcat);

  hipLaunchKernelGGL((k_gemm_bt<short, false>), dim3(32, 256), dim3(256), 0, stream,
                     xbf, Wxt, bcat, XG, 32768, 4096, 1024);

  hipMemsetAsync(bar, 0, 4096, stream);

  {
    void* args[] = { (void*)&XG, (void*)&Wht, (void*)&hbuf, (void*)&bar, (void*)&HS };
    hipLaunchCooperativeKernel((void*)k_lstm_p, dim3(128), dim3(512), args, 0, stream);
  }

  hipLaunchKernelGGL((k_gemm_bt<float, true>), dim3(8, 256), dim3(256), 0, stream,
                     HS, Whyt, by, (float*)d_out, 32768, 1024, 1024);
}

// Round 4
// 5188.943 us; speedup vs baseline: 3.4765x; 1.0274x over previous
//
#include <hip/hip_runtime.h>
#include <hip/hip_bf16.h>

typedef __attribute__((ext_vector_type(8))) short s8;
typedef __attribute__((ext_vector_type(4))) float f4;

#define DEVI static __device__ __forceinline__

DEVI float bf2f(short u) {
  union { float f; unsigned int i; } v;
  v.i = ((unsigned int)(unsigned short)u) << 16;
  return v.f;
}
DEVI short f2bf(float f) {
  union { float f; unsigned int i; } v; v.f = f;
  unsigned int r = v.i + 0x7fffu + ((v.i >> 16) & 1u);
  return (short)(r >> 16);
}
DEVI void gload_lds16(const void* g, void* l) {
  __builtin_amdgcn_global_load_lds(
      (const __attribute__((address_space(1))) unsigned int*)g,
      (__attribute__((address_space(3))) unsigned int*)l, 16, 0, 0);
}
DEVI float sigm(float x) { return 1.f / (1.f + __expf(-x)); }

// ---------------- converts ----------------
// x [64][512][1024] f32  ->  xbf [512][64][1024] bf16 (t-major rows)
__global__ void k_x_relayout(const float* __restrict__ in, short* __restrict__ out) {
  long idx8 = (long)blockIdx.x * blockDim.x + threadIdx.x;
  long E = idx8 * 8;
  long row = E >> 10;
  long col = E & 1023;
  long t = row >> 6, b = row & 63;
  const float* src = in + ((b << 9) + t) * 1024 + col;
  float4 a = *(const float4*)(src);
  float4 c = *(const float4*)(src + 4);
  s8 o;
  o[0] = f2bf(a.x); o[1] = f2bf(a.y); o[2] = f2bf(a.z); o[3] = f2bf(a.w);
  o[4] = f2bf(c.x); o[5] = f2bf(c.y); o[6] = f2bf(c.z); o[7] = f2bf(c.w);
  *(s8*)(out + E) = o;
}

// src [1024][1024] f32 row-major [k][n]  ->  dst [1024][1024] bf16 at [n][k]
__global__ void k_transpose_c(const float* __restrict__ src, short* __restrict__ dst) {
  __shared__ float tile[32][33];
  int n0 = blockIdx.x * 32, k0 = blockIdx.y * 32;
  int lx = threadIdx.x & 31, ly = threadIdx.x >> 5;
#pragma unroll
  for (int r = 0; r < 32; r += 8)
    tile[ly + r][lx] = src[(long)(k0 + ly + r) * 1024 + n0 + lx];
  __syncthreads();
#pragma unroll
  for (int r = 0; r < 32; r += 8)
    dst[(long)(n0 + ly + r) * 1024 + k0 + lx] = f2bf(tile[lx][ly + r]);
}

__global__ void k_bcat(const float* __restrict__ b0, const float* __restrict__ b1,
                       const float* __restrict__ b2, const float* __restrict__ b3,
                       float* __restrict__ o) {
  int i = blockIdx.x * 256 + threadIdx.x;
  int j = i & 1023;
  float v;
  switch (i >> 10) { case 0: v = b0[j]; break; case 1: v = b1[j]; break;
                     case 2: v = b2[j]; break; default: v = b3[j]; }
  o[i] = v;
}

// ---------------- bf16 GEMM: C[M][N] = A[M][K] @ Bt[N][K]^T + bias ----------------
// REMAP 0: linear. 1: row (t*64+b) -> (b*512+t). 2: XG permute [t][rb][ug][g][16r][32u].
template <typename OutT, int REMAP>
__global__ __launch_bounds__(256) void k_gemm_bt(
    const short* __restrict__ A, const short* __restrict__ Bt,
    const float* __restrict__ bias, OutT* __restrict__ C,
    int M, int N, int K) {
  __shared__ __align__(16) char As[8192];
  __shared__ __align__(16) char Bs[8192];
  const int tid = threadIdx.x;
  const int wid = tid >> 6, lane = tid & 63;
  const int lr = lane & 15, lk = lane >> 4;
  const int wy = wid >> 1, wx = wid & 1;
  const long bm = (long)blockIdx.y * 128, bn = (long)blockIdx.x * 128;
  const char* Ab = (const char*)A;
  const char* Bb = (const char*)Bt;
  f4 acc[4][4];
#pragma unroll
  for (int i = 0; i < 4; ++i)
#pragma unroll
    for (int j = 0; j < 4; ++j) acc[i][j] = f4{0.f, 0.f, 0.f, 0.f};

  for (int k0 = 0; k0 < K; k0 += 32) {
#pragma unroll
    for (int p = 0; p < 2; ++p) {
      int off = p * 4096 + tid * 16;
      int r = off >> 6, cb = off & 63;
      int sw = cb ^ ((r & 3) << 4);
      gload_lds16(Ab + ((bm + r) * K + k0) * 2 + sw, As + p * 4096 + wid * 1024);
      gload_lds16(Bb + ((bn + r) * K + k0) * 2 + sw, Bs + p * 4096 + wid * 1024);
    }
    __syncthreads();
    s8 af[4], bfr[4];
#pragma unroll
    for (int mi = 0; mi < 4; ++mi) {
      int r = wy * 64 + mi * 16 + lr;
      int x = r * 64 + lk * 16;
      af[mi] = *(const s8*)(As + (x ^ ((r & 3) << 4)));
    }
#pragma unroll
    for (int ni = 0; ni < 4; ++ni) {
      int r = wx * 64 + ni * 16 + lr;
      int x = r * 64 + lk * 16;
      bfr[ni] = *(const s8*)(Bs + (x ^ ((r & 3) << 4)));
    }
#pragma unroll
    for (int mi = 0; mi < 4; ++mi)
#pragma unroll
      for (int ni = 0; ni < 4; ++ni)
        acc[mi][ni] = __builtin_amdgcn_mfma_f32_16x16x32_bf16(af[mi], bfr[ni], acc[mi][ni], 0, 0, 0);
    __syncthreads();
  }
#pragma unroll
  for (int mi = 0; mi < 4; ++mi)
#pragma unroll
    for (int ni = 0; ni < 4; ++ni)
#pragma unroll
      for (int j = 0; j < 4; ++j) {
        long row = bm + wy * 64 + mi * 16 + lk * 4 + j;
        long col = bn + wx * 64 + ni * 16 + lr;
        float v = acc[mi][ni][j] + bias[col];
        long off;
        if constexpr (REMAP == 1) {
          off = ((row & 63) * 512 + (row >> 6)) * (long)N + col;
        } else if constexpr (REMAP == 2) {
          long tt = row >> 6, b = row & 63;
          long gg = col >> 10, u = col & 1023;
          off = ((((tt << 2) + (b >> 4)) << 5) + (u >> 5)) * 2048 +
                (gg << 9) + ((b & 15) << 5) + (u & 31);
        } else {
          off = row * (long)N + col;
        }
        if constexpr (sizeof(OutT) == 2) C[off] = f2bf(v);
        else                              C[off] = v;
      }
}

// ---------------- persistent LSTM recurrence ----------------
// 128 WGs x 512 threads. WG = (rb = wg&3: 16 batch rows) x (ug = wg>>2: 32 units).
// Wave (g = wid&3, uh = wid>>2): gate g, unit cols ug*32+uh*16+[0,16).
// Weights pinned in VGPRs (asm keep-alive); c in a register; h (hi,lo packed u32)
// via relaxed agent-scope atomics (IF$-coherent). Sync: per-rb 32-flag poll.
__global__ __launch_bounds__(512, 2) void k_lstm_p(
    const short* __restrict__ XG,     // [512][4][32][2048] permuted, bias folded
    const short* __restrict__ Wht,    // [4096][1024]
    unsigned int* __restrict__ hbuf,  // [2][64][1024] packed (hi<<16 | lo)
    unsigned int* __restrict__ bar,   // flags[rb*32+ug] spaced 16 u32 (64 B)
    short* __restrict__ HS) {         // [512][64][1024] bf16 (hi only)
  __shared__ __align__(16) char hHi[32768];  // [16][1024] bf16, XOR-swizzled
  __shared__ __align__(16) char hLo[32768];
  __shared__ float pre[4 * 16 * 33];

  const int tid = threadIdx.x;
  const int wg = blockIdx.x;
  const int wid = tid >> 6, lane = tid & 63;
  const int lr = lane & 15, lk = lane >> 4;
  const int g = wid & 3, uh = wid >> 2;
  const int rb = wg & 3, ug = wg >> 2;
  const int gcol = g * 1024 + ug * 32 + uh * 16 + lr;

  // recurrent-weight B-fragments: 32 x bf16x8 = 128 VGPR, held all 512 steps
  s8 wf[32];
  {
    const short* wrow = Wht + (long)gcol * 1024 + lk * 8;
#pragma unroll
    for (int kc = 0; kc < 32; ++kc) wf[kc] = *(const s8*)(wrow + kc * 32);
  }
  // pin in VGPRs: opaque "modification" prevents rematerialization from Wht
#pragma unroll
  for (int kc = 0; kc < 32; ++kc) asm volatile("" : "+v"(wf[kc]));

  const int erow = tid >> 5, eu = tid & 31;
  const int growE = rb * 16 + erow;
  const int ucolE = ug * 32 + eu;
  const int srow = tid >> 5, sL = tid & 31;
  float c = 0.f;

  // h0 = 0 (parity 0), publish flag = 1
  __hip_atomic_store(&hbuf[(long)growE * 1024 + ucolE], 0u,
                     __ATOMIC_RELAXED, __HIP_MEMORY_SCOPE_AGENT);
  asm volatile("s_waitcnt vmcnt(0)" ::: "memory");
  __syncthreads();
  if (tid == 0)
    __hip_atomic_store(&bar[((rb << 5) + ug) << 4], 1u,
                       __ATOMIC_RELAXED, __HIP_MEMORY_SCOPE_AGENT);

  // XG prefetch for t=0
  short nx0, nx1, nx2, nx3;
  {
    const short* xp = XG + (long)(rb * 32 + ug) * 2048 + g * 512 + lk * 128 + uh * 16 + lr;
    nx0 = xp[0]; nx1 = xp[32]; nx2 = xp[64]; nx3 = xp[96];
  }

  for (int t = 0; t < 512; ++t) {
    // wait: all 32 unit-group producers of this rb published h_t
    {
      const unsigned int target = (unsigned int)(t + 1);
      if (lane < 32) {
        int guard = 0;
        while (__hip_atomic_load(&bar[((rb << 5) + lane) << 4],
                                 __ATOMIC_RELAXED, __HIP_MEMORY_SCOPE_AGENT) < target) {
          __builtin_amdgcn_s_sleep(1);
          if (++guard > (1 << 20)) break;
        }
      }
    }
    const unsigned int* cur = hbuf + (t & 1) * 65536;
    unsigned int* nxt = hbuf + ((t + 1) & 1) * 65536;

    // stage h rows [rb*16, +16): packed u64 loads -> split hi/lo -> swizzled LDS
    {
      const unsigned long long* src =
          (const unsigned long long*)(cur + (long)(rb * 16 + srow) * 1024);
#pragma unroll
      for (int i = 0; i < 16; ++i) {
        unsigned long long v = __hip_atomic_load(&src[sL + i * 32],
                                                 __ATOMIC_RELAXED, __HIP_MEMORY_SCOPE_AGENT);
        unsigned int w0 = (unsigned int)v, w1 = (unsigned int)(v >> 32);
        unsigned int hiW = __builtin_amdgcn_perm(w1, w0, 0x07060302u);
        unsigned int loW = __builtin_amdgcn_perm(w1, w0, 0x05040100u);
        int a = (srow * 2048 + sL * 4 + i * 128) ^ ((srow & 7) << 4);
        *(unsigned int*)(hHi + a) = hiW;
        *(unsigned int*)(hLo + a) = loW;
      }
    }

    // consume step-t xg, then prefetch t+1 (drained by barrier vmcnt)
    float xg0 = bf2f(nx0), xg1 = bf2f(nx1), xg2 = bf2f(nx2), xg3 = bf2f(nx3);
    {
      int tn = (t + 1) & 511;
      const short* xp = XG + (long)((tn * 4 + rb) * 32 + ug) * 2048 + g * 512 + lk * 128 + uh * 16 + lr;
      nx0 = xp[0]; nx1 = xp[32]; nx2 = xp[64]; nx3 = xp[96];
    }
    __syncthreads();

    // 4 independent MFMA chains (16 deep each)
    f4 aHe{0.f, 0.f, 0.f, 0.f}, aHo{0.f, 0.f, 0.f, 0.f};
    f4 aLe{0.f, 0.f, 0.f, 0.f}, aLo{0.f, 0.f, 0.f, 0.f};
#pragma unroll
    for (int kc = 0; kc < 32; kc += 2) {
      int a0 = (lr * 2048 + kc * 64 + lk * 16) ^ ((lr & 7) << 4);
      int a1 = (lr * 2048 + (kc + 1) * 64 + lk * 16) ^ ((lr & 7) << 4);
      aHe = __builtin_amdgcn_mfma_f32_16x16x32_bf16(*(const s8*)(hHi + a0), wf[kc], aHe, 0, 0, 0);
      aHo = __builtin_amdgcn_mfma_f32_16x16x32_bf16(*(const s8*)(hHi + a1), wf[kc + 1], aHo, 0, 0, 0);
      aLe = __builtin_amdgcn_mfma_f32_16x16x32_bf16(*(const s8*)(hLo + a0), wf[kc], aLe, 0, 0, 0);
      aLo = __builtin_amdgcn_mfma_f32_16x16x32_bf16(*(const s8*)(hLo + a1), wf[kc + 1], aLo, 0, 0, 0);
    }

    // exchange gate pre-activations (C/D layout: col=lr, row=lk*4+j)
    {
      float xgf[4] = {xg0, xg1, xg2, xg3};
#pragma unroll
      for (int j = 0; j < 4; ++j)
        pre[(g * 16 + lk * 4 + j) * 33 + uh * 16 + lr] =
            aHe[j] + aHo[j] + aLe[j] + aLo[j] + xgf[j];
    }
    __syncthreads();

    // elementwise state update
    {
      float pi = pre[(0 * 16 + erow) * 33 + eu];
      float pf = pre[(1 * 16 + erow) * 33 + eu];
      float po = pre[(2 * 16 + erow) * 33 + eu];
      float pc = pre[(3 * 16 + erow) * 33 + eu];
      float fi = sigm(pi), ff = sigm(pf), fo = sigm(po);
      float ch = tanhf(pc);
      c = ff * c + fi * ch;
      float h = fo * tanhf(c);
      short hh = f2bf(h);
      short hl = f2bf(h - bf2f(hh));
      unsigned int w = ((unsigned int)(unsigned short)hh << 16) | (unsigned short)hl;
      __hip_atomic_store(&nxt[(long)growE * 1024 + ucolE], w,
                         __ATOMIC_RELAXED, __HIP_MEMORY_SCOPE_AGENT);
      HS[(long)t * 65536 + (long)growE * 1024 + ucolE] = hh;
    }
    // publish: drain own stores, WG-converge, set flag
    asm volatile("s_waitcnt vmcnt(0)" ::: "memory");
    __syncthreads();
    if (tid == 0)
      __hip_atomic_store(&bar[((rb << 5) + ug) << 4], (unsigned int)(t + 2),
                         __ATOMIC_RELAXED, __HIP_MEMORY_SCOPE_AGENT);
  }
}

// ---------------- launch ----------------
extern "C" void kernel_launch(void* const* d_in, const int* in_sizes, int n_in,
                              void* d_out, int out_size, void* d_ws, size_t ws_size,
                              hipStream_t stream) {
  const float* x = (const float*)d_in[0];
  const float* Wx[4] = {(const float*)d_in[1], (const float*)d_in[4], (const float*)d_in[7], (const float*)d_in[10]};
  const float* Wh[4] = {(const float*)d_in[2], (const float*)d_in[5], (const float*)d_in[8], (const float*)d_in[11]};
  const float* bg[4] = {(const float*)d_in[3], (const float*)d_in[6], (const float*)d_in[9], (const float*)d_in[12]};
  const float* Why = (const float*)d_in[13];
  const float* by  = (const float*)d_in[14];

  char* ws = (char*)d_ws;                     // layout (bytes):
  short* xbf  = (short*)(ws);                 // 67,108,864  x bf16 [512][64][1024]
  short* HS   = (short*)(ws);                 // reuses xbf (dead after big GEMM)
  short* Wxt  = (short*)(ws + 67108864);      //  8,388,608
  short* Wht  = (short*)(ws + 75497472);      //  8,388,608
  short* Whyt = (short*)(ws + 83886080);      //  2,097,152
  float* bcat = (float*)(ws + 85983232);      //     16,384
  short* XG   = (short*)(ws + 85999616);      // 268,435,456 [512][4][32][2048] permuted
  unsigned int* hbuf = (unsigned int*)(ws + 354435072);  // 524,288
  unsigned int* bar  = (unsigned int*)(ws + 354959360);  //  16,384

  hipLaunchKernelGGL(k_x_relayout, dim3(16384), dim3(256), 0, stream, x, xbf);
  for (int gi = 0; gi < 4; ++gi) {
    hipLaunchKernelGGL(k_transpose_c, dim3(32, 32), dim3(256), 0, stream, Wx[gi], Wxt + (long)gi * 1048576);
    hipLaunchKernelGGL(k_transpose_c, dim3(32, 32), dim3(256), 0, stream, Wh[gi], Wht + (long)gi * 1048576);
  }
  hipLaunchKernelGGL(k_transpose_c, dim3(32, 32), dim3(256), 0, stream, Why, Whyt);
  hipLaunchKernelGGL(k_bcat, dim3(16), dim3(256), 0, stream, bg[0], bg[1], bg[2], bg[3], bcat);

  hipLaunchKernelGGL((k_gemm_bt<short, 2>), dim3(32, 256), dim3(256), 0, stream,
                     xbf, Wxt, bcat, XG, 32768, 4096, 1024);

  hipMemsetAsync(bar, 0, 16384, stream);

  {
    void* args[] = { (void*)&XG, (void*)&Wht, (void*)&hbuf, (void*)&bar, (void*)&HS };
    hipLaunchCooperativeKernel((void*)k_lstm_p, dim3(128), dim3(512), args, 0, stream);
  }

  hipLaunchKernelGGL((k_gemm_bt<float, 1>), dim3(8, 256), dim3(256), 0, stream,
                     HS, Whyt, by, (float*)d_out, 32768, 1024, 1024);
}